// Round 2
// baseline (414.673 us; speedup 1.0000x reference)
//
#include <hip/hip_runtime.h>
#include <math.h>

#define CAP 48  // max bucketed in-degree; in-degree ~ Poisson(16), P(deg>=48) ~ 8e-11/node

__device__ __forceinline__ float leaky(float x){ return x > 0.f ? x : 0.2f * x; }
__device__ __forceinline__ float eluf(float x){ return x > 0.f ? x : __expf(x) - 1.f; }

// K0: collapse att_src1/att_dst1 through W1: v[f][h] = sum_c W1[f, h*64+c] * att[h][c]
__global__ void k0_vw(const float* __restrict__ W1, const float* __restrict__ as1,
                      const float* __restrict__ ad1, float* __restrict__ vw){
  int t = threadIdx.x;
  if (t >= 48) return;
  int side = t / 24;
  int r = t % 24, f = r / 4, h = r % 4;
  const float* att = side ? ad1 : as1;
  float s = 0.f;
  for (int c = 0; c < 64; ++c) s += W1[f*256 + h*64 + c] * att[h*64 + c];
  vw[side*24 + f*4 + h] = s;
}

// K1: per-node attention logit halves for layer 1: a_src1/a_dst1 [N,4]
__global__ __launch_bounds__(256) void k1_att1(const float* __restrict__ x,
    const float* __restrict__ vw, float* __restrict__ a_src1,
    float* __restrict__ a_dst1, int N){
  int n = blockIdx.x * blockDim.x + threadIdx.x;
  if (n >= N) return;
  float xf[6];
  for (int f = 0; f < 6; ++f) xf[f] = x[n*6 + f];
  for (int h = 0; h < 4; ++h){
    float s = 0.f, d = 0.f;
    for (int f = 0; f < 6; ++f){ s += xf[f] * vw[f*4 + h]; d += xf[f] * vw[24 + f*4 + h]; }
    a_src1[n*4 + h] = s;
    a_dst1[n*4 + h] = d;
  }
}

// K2: bucket edges by dst (CSR-lite, fixed capacity). Self-loops handled analytically later.
// NOTE: harness passes integer inputs as int32 (NOT int64) — edge_index is const int*.
__global__ __launch_bounds__(256) void k2_bucket(const int* __restrict__ ei, int E,
    int* __restrict__ cnt, int* __restrict__ bucket){
  int e = blockIdx.x * blockDim.x + threadIdx.x;
  if (e >= E) return;
  int src = ei[e];
  int dst = ei[E + e];
  int pos = atomicAdd(&cnt[dst], 1);
  if (pos < CAP) bucket[dst*CAP + pos] = src;
}

// K3: layer-1 softmax-aggregate in INPUT space: agg1[n,h,f] = sum_e exp(alpha_e)*x[src,f]
// (self-loop included analytically; denominator applied later). No atomics: gather per dst.
__global__ __launch_bounds__(256) void k3_agg1(const float* __restrict__ x,
    const float* __restrict__ a_src1, const float* __restrict__ a_dst1,
    const int* __restrict__ cnt, const int* __restrict__ bucket,
    float* __restrict__ denom1, float* __restrict__ agg1, int N){
  int t = blockIdx.x * blockDim.x + threadIdx.x;
  if (t >= N*4) return;
  int n = t >> 2, h = t & 3;
  float ad = a_dst1[t];
  float e0 = __expf(leaky(a_src1[t] + ad));   // self-loop term
  float den = e0;
  float acc[6];
  for (int f = 0; f < 6; ++f) acc[f] = e0 * x[n*6 + f];
  int deg = min(cnt[n], CAP);
  for (int i = 0; i < deg; ++i){
    int s = bucket[n*CAP + i];
    float e = __expf(leaky(a_src1[s*4 + h] + ad));
    den += e;
    for (int f = 0; f < 6; ++f) acc[f] += e * x[s*6 + f];
  }
  denom1[t] = den;
  for (int f = 0; f < 6; ++f) agg1[t*6 + f] = acc[f];
}

// K4: fused layer-1 epilogue + layer-2 input GEMM:
//   helu1[n,k] = elu( dot(agg1[n, k/64, :], W1[:, k]) / denom1[n, k/64] + b1[k] )  (into LDS)
//   h2[n,c]    = sum_k helu1[n,k] * W2[k,c]
//   a_src2[n]  = sum_c h2[n,c]*att_src2[c]  (and a_dst2)
__global__ __launch_bounds__(256) void k4_layer2pre(
    const float* __restrict__ agg1, const float* __restrict__ denom1,
    const float* __restrict__ W1, const float* __restrict__ b1,
    const float* __restrict__ W2, const float* __restrict__ as2v,
    const float* __restrict__ ad2v, float* __restrict__ h2,
    float* __restrict__ a_src2, float* __restrict__ a_dst2, int N){
  __shared__ float tmp[64*64];   // [kk][m]
  __shared__ float w2s[64*64];   // [kk][c]
  int t = threadIdx.x;
  int lane = t & 63;
  int w = t >> 6;                // wave id 0..3
  int base = blockIdx.x * 64;
  float acc[16];
  for (int j = 0; j < 16; ++j) acc[j] = 0.f;

  for (int kc = 0; kc < 4; ++kc){
    for (int i = 0; i < 16; ++i){
      int idx = t + 256*i;
      w2s[idx] = W2[kc*4096 + idx];
    }
    int n = min(base + lane, N-1);
    float dinv = 1.f / denom1[n*4 + kc];
    float af[6];
    for (int f = 0; f < 6; ++f) af[f] = agg1[(n*4 + kc)*6 + f] * dinv;
    for (int j = 0; j < 16; ++j){
      int kk = w*16 + j;
      int K = kc*64 + kk;
      float s = b1[K];
      for (int f = 0; f < 6; ++f) s += af[f] * W1[f*256 + K];
      tmp[kk*64 + lane] = eluf(s);
    }
    __syncthreads();
    for (int kk = 0; kk < 64; ++kk){
      float w2v = w2s[kk*64 + lane];
      const float4* tr = (const float4*)(&tmp[kk*64 + w*16]);
      float4 t0 = tr[0], t1 = tr[1], t2 = tr[2], t3 = tr[3];
      acc[0]  += t0.x*w2v; acc[1]  += t0.y*w2v; acc[2]  += t0.z*w2v; acc[3]  += t0.w*w2v;
      acc[4]  += t1.x*w2v; acc[5]  += t1.y*w2v; acc[6]  += t1.z*w2v; acc[7]  += t1.w*w2v;
      acc[8]  += t2.x*w2v; acc[9]  += t2.y*w2v; acc[10] += t2.z*w2v; acc[11] += t2.w*w2v;
      acc[12] += t3.x*w2v; acc[13] += t3.y*w2v; acc[14] += t3.z*w2v; acc[15] += t3.w*w2v;
    }
    __syncthreads();
  }
  float asv = as2v[lane], adv = ad2v[lane];
  for (int j = 0; j < 16; ++j){
    int n = base + w*16 + j;
    if (n < N) h2[n*64 + lane] = acc[j];
    float ps = acc[j] * asv, pd = acc[j] * adv;
    for (int o = 32; o > 0; o >>= 1){
      ps += __shfl_down(ps, o, 64);
      pd += __shfl_down(pd, o, 64);
    }
    if (lane == 0 && n < N){ a_src2[n] = ps; a_dst2[n] = pd; }
  }
}

// K5: layer-2 aggregation ONLY for drone dst nodes (first ND), fused with elu + MLP head.
__global__ __launch_bounds__(256) void k5_out(
    const float* __restrict__ h2, const float* __restrict__ a_src2,
    const float* __restrict__ a_dst2, const int* __restrict__ cnt,
    const int* __restrict__ bucket, const float* __restrict__ b2,
    const float* __restrict__ fc1w, const float* __restrict__ fc1b,
    const float* __restrict__ fc2w, const float* __restrict__ fc2b,
    float* __restrict__ out, int ND){
  __shared__ float hb[4][64];
  int lane = threadIdx.x & 63;
  int w = threadIdx.x >> 6;
  int n = blockIdx.x * 4 + w;     // drone id == node id (first ND nodes are drones)
  if (n >= ND) return;
  float adv = a_dst2[n];
  float e0 = __expf(leaky(a_src2[n] + adv));
  float den = e0;
  float acc = e0 * h2[n*64 + lane];
  int deg = min(cnt[n], CAP);
  for (int i = 0; i < deg; ++i){
    int s = bucket[n*CAP + i];
    float e = __expf(leaky(a_src2[s] + adv));
    den += e;
    acc += e * h2[s*64 + lane];
  }
  float hv = eluf(acc / den + b2[lane]);
  hb[w][lane] = hv;               // wave-local LDS (lockstep wave64)
  float t1 = fc1b[lane];
  for (int k = 0; k < 64; ++k) t1 += hb[w][k] * fc1w[k*64 + lane];
  t1 = fmaxf(t1, 0.f);
  float p0 = t1 * fc2w[lane*2 + 0];
  float p1 = t1 * fc2w[lane*2 + 1];
  for (int o = 32; o > 0; o >>= 1){
    p0 += __shfl_down(p0, o, 64);
    p1 += __shfl_down(p1, o, 64);
  }
  if (lane == 0){
    out[n*2 + 0] = tanhf(p0 + fc2b[0]) * 2.f;
    out[n*2 + 1] = tanhf(p1 + fc2b[1]) * 2.f;
  }
}

extern "C" void kernel_launch(void* const* d_in, const int* in_sizes, int n_in,
                              void* d_out, int out_size, void* d_ws, size_t ws_size,
                              hipStream_t stream){
  const float* x    = (const float*)d_in[0];
  const int*   ei   = (const int*)d_in[1];    // harness passes integers as int32
  const float* W1   = (const float*)d_in[3];
  const float* as1  = (const float*)d_in[4];
  const float* ad1  = (const float*)d_in[5];
  const float* b1   = (const float*)d_in[6];
  const float* W2   = (const float*)d_in[7];
  const float* as2  = (const float*)d_in[8];
  const float* ad2  = (const float*)d_in[9];
  const float* b2   = (const float*)d_in[10];
  const float* fc1w = (const float*)d_in[11];
  const float* fc1b = (const float*)d_in[12];
  const float* fc2w = (const float*)d_in[13];
  const float* fc2b = (const float*)d_in[14];
  float* out = (float*)d_out;

  int N  = in_sizes[0] / 6;
  int E  = in_sizes[1] / 2;
  int ND = out_size / 2;

  char* p = (char*)d_ws;
  auto alloc = [&](size_t bytes){ void* r = (void*)p; p += (bytes + 255) & ~(size_t)255; return r; };
  int*   cnt    = (int*)  alloc((size_t)N * 4);
  int*   bucket = (int*)  alloc((size_t)N * CAP * 4);
  float* a_src1 = (float*)alloc((size_t)N * 16);
  float* a_dst1 = (float*)alloc((size_t)N * 16);
  float* denom1 = (float*)alloc((size_t)N * 16);
  float* agg1   = (float*)alloc((size_t)N * 96);
  float* h2     = (float*)alloc((size_t)N * 256);
  float* a_src2 = (float*)alloc((size_t)N * 4);
  float* a_dst2 = (float*)alloc((size_t)N * 4);
  float* vw     = (float*)alloc(48 * 4);

  // Guard: if workspace is too small, bail cleanly (absmax failure, not a GPU fault).
  size_t needed = (size_t)(p - (char*)d_ws);
  if (needed > ws_size) return;

  hipMemsetAsync(cnt, 0, (size_t)N * 4, stream);
  k0_vw<<<1, 64, 0, stream>>>(W1, as1, ad1, vw);
  k1_att1<<<(N + 255)/256, 256, 0, stream>>>(x, vw, a_src1, a_dst1, N);
  k2_bucket<<<(E + 255)/256, 256, 0, stream>>>(ei, E, cnt, bucket);
  k3_agg1<<<(N*4 + 255)/256, 256, 0, stream>>>(x, a_src1, a_dst1, cnt, bucket, denom1, agg1, N);
  k4_layer2pre<<<(N + 63)/64, 256, 0, stream>>>(agg1, denom1, W1, b1, W2, as2, ad2,
                                                h2, a_src2, a_dst2, N);
  k5_out<<<(ND + 3)/4, 256, 0, stream>>>(h2, a_src2, a_dst2, cnt, bucket, b2,
                                         fc1w, fc1b, fc2w, fc2b, out, ND);
}

// Round 3
// 351.693 us; speedup vs baseline: 1.1791x; 1.1791x over previous
//
#include <hip/hip_runtime.h>
#include <math.h>

#define CAP 48     // max bucketed in-degree; Poisson(16), P(deg>=48) ~ 8e-11/node
#define NPART 8    // dst partitions ~ XCDs

__device__ __forceinline__ float leaky(float x){ return x > 0.f ? x : 0.2f * x; }
__device__ __forceinline__ float eluf(float x){ return x > 0.f ? x : __expf(x) - 1.f; }

// K1 (fused old k0+k1): compute vw in LDS, emit packed 64B node record:
// rec[n] = {x0..x5, as0..as3, ad0..ad3, pad, pad}  (4 x float4)
__global__ __launch_bounds__(256) void k1_att1(const float* __restrict__ x,
    const float* __restrict__ W1, const float* __restrict__ as1,
    const float* __restrict__ ad1, float4* __restrict__ rec, int N){
  __shared__ float vw[48];
  int t = threadIdx.x;
  if (t < 48){
    int side = t / 24, r = t % 24, f = r / 4, h = r % 4;
    const float* att = side ? ad1 : as1;
    float s = 0.f;
    for (int c = 0; c < 64; ++c) s += W1[f*256 + h*64 + c] * att[h*64 + c];
    vw[side*24 + f*4 + h] = s;
  }
  __syncthreads();
  int n = blockIdx.x * 256 + t;
  if (n >= N) return;
  float xf[6];
  for (int f = 0; f < 6; ++f) xf[f] = x[n*6 + f];
  float as[4], ad[4];
  for (int h = 0; h < 4; ++h){
    float s = 0.f, d = 0.f;
    for (int f = 0; f < 6; ++f){ s += xf[f] * vw[f*4 + h]; d += xf[f] * vw[24 + f*4 + h]; }
    as[h] = s; ad[h] = d;
  }
  rec[n*4 + 0] = make_float4(xf[0], xf[1], xf[2], xf[3]);
  rec[n*4 + 1] = make_float4(xf[4], xf[5], as[0], as[1]);
  rec[n*4 + 2] = make_float4(as[2], as[3], ad[0], ad[1]);
  rec[n*4 + 3] = make_float4(ad[2], ad[3], 0.f, 0.f);
}

// K2: XCD-partitioned bucket build. Group p = blockIdx&7 handles dst in
// [p*PART, (p+1)*PART): partition bucket slab (2.4MB) stays in one XCD's L2,
// so scattered 4B stores coalesce in L2 instead of 64B-line HBM writebacks.
__global__ __launch_bounds__(256) void k2_bucket(const int* __restrict__ ei,
    int E, int N, int* __restrict__ cnt, int* __restrict__ bucket){
  int part = (N + NPART - 1) / NPART;
  int p = blockIdx.x & (NPART - 1);
  int lo = p * part;
  int hi = min(N, lo + part);
  int g = blockIdx.x >> 3;                 // block index within group
  int tid = g * 256 + threadIdx.x;
  int stride = (gridDim.x >> 3) * 256;
  for (int e = tid; e < E; e += stride){
    int dst = ei[E + e];
    if (dst >= lo && dst < hi){
      int pos = atomicAdd(&cnt[dst], 1);
      if (pos < CAP) bucket[dst*CAP + pos] = ei[e];
    }
  }
}

// K3: per-NODE layer-1 softmax-aggregate in input space, all 4 heads at once.
// One 64B record gather per edge (was ~4 lines x 4 heads). 2-edge pipeline for MLP.
// Output packed 128B/node: aggr[n*32 + h*6 + f] = acc, aggr[n*32 + 24 + h] = den.
__global__ __launch_bounds__(256) void k3_agg1(const float4* __restrict__ rec,
    const int* __restrict__ cnt, const int* __restrict__ bucket,
    float* __restrict__ aggr, int N){
  int n = blockIdx.x * 256 + threadIdx.x;
  if (n >= N) return;
  float4 q0 = rec[n*4+0], q1 = rec[n*4+1], q2 = rec[n*4+2], q3 = rec[n*4+3];
  float xf[6] = {q0.x, q0.y, q0.z, q0.w, q1.x, q1.y};
  float as[4] = {q1.z, q1.w, q2.x, q2.y};
  float ad[4] = {q2.z, q2.w, q3.x, q3.y};
  float acc[4][6], den[4];
  for (int h = 0; h < 4; ++h){
    float e0 = __expf(leaky(as[h] + ad[h]));   // self-loop
    den[h] = e0;
    for (int f = 0; f < 6; ++f) acc[h][f] = e0 * xf[f];
  }
  int deg = min(cnt[n], CAP);
  const int* bk = bucket + n*CAP;
  int i = 0;
  for (; i + 2 <= deg; i += 2){
    int s0 = bk[i], s1 = bk[i+1];
    float4 a0 = rec[s0*4+0], a1 = rec[s0*4+1], a2 = rec[s0*4+2];
    float4 b0 = rec[s1*4+0], b1 = rec[s1*4+1], b2 = rec[s1*4+2];
    float sx0[6] = {a0.x, a0.y, a0.z, a0.w, a1.x, a1.y};
    float sa0[4] = {a1.z, a1.w, a2.x, a2.y};
    float sx1[6] = {b0.x, b0.y, b0.z, b0.w, b1.x, b1.y};
    float sa1[4] = {b1.z, b1.w, b2.x, b2.y};
    for (int h = 0; h < 4; ++h){
      float e0 = __expf(leaky(sa0[h] + ad[h]));
      float e1 = __expf(leaky(sa1[h] + ad[h]));
      den[h] += e0 + e1;
      for (int f = 0; f < 6; ++f) acc[h][f] += e0 * sx0[f] + e1 * sx1[f];
    }
  }
  if (i < deg){
    int s = bk[i];
    float4 a0 = rec[s*4+0], a1 = rec[s*4+1], a2 = rec[s*4+2];
    float sx[6] = {a0.x, a0.y, a0.z, a0.w, a1.x, a1.y};
    float sa[4] = {a1.z, a1.w, a2.x, a2.y};
    for (int h = 0; h < 4; ++h){
      float e = __expf(leaky(sa[h] + ad[h]));
      den[h] += e;
      for (int f = 0; f < 6; ++f) acc[h][f] += e * sx[f];
    }
  }
  float4* o = (float4*)(aggr + (size_t)n*32);
  o[0] = make_float4(acc[0][0], acc[0][1], acc[0][2], acc[0][3]);
  o[1] = make_float4(acc[0][4], acc[0][5], acc[1][0], acc[1][1]);
  o[2] = make_float4(acc[1][2], acc[1][3], acc[1][4], acc[1][5]);
  o[3] = make_float4(acc[2][0], acc[2][1], acc[2][2], acc[2][3]);
  o[4] = make_float4(acc[2][4], acc[2][5], acc[3][0], acc[3][1]);
  o[5] = make_float4(acc[3][2], acc[3][3], acc[3][4], acc[3][5]);
  o[6] = make_float4(den[0], den[1], den[2], den[3]);
}

// K4: fused layer-1 epilogue + layer-2 input GEMM + layer-2 attention dots.
__global__ __launch_bounds__(256) void k4_layer2pre(
    const float* __restrict__ aggr, const float* __restrict__ W1,
    const float* __restrict__ b1, const float* __restrict__ W2,
    const float* __restrict__ as2v, const float* __restrict__ ad2v,
    float* __restrict__ h2, float2* __restrict__ a2, int N){
  __shared__ float tmp[64*64];   // [kk][m]
  __shared__ float w2s[64*64];   // [kk][c]
  int t = threadIdx.x;
  int lane = t & 63;
  int w = t >> 6;
  int base = blockIdx.x * 64;
  float acc[16];
  for (int j = 0; j < 16; ++j) acc[j] = 0.f;

  for (int kc = 0; kc < 4; ++kc){
    for (int i = 0; i < 16; ++i){
      int idx = t + 256*i;
      w2s[idx] = W2[kc*4096 + idx];
    }
    int n = min(base + lane, N-1);
    const float* A = aggr + (size_t)n*32;
    float dinv = 1.f / A[24 + kc];
    float af[6];
    for (int f = 0; f < 6; ++f) af[f] = A[kc*6 + f] * dinv;
    for (int j = 0; j < 16; ++j){
      int kk = w*16 + j;
      int K = kc*64 + kk;
      float s = b1[K];
      for (int f = 0; f < 6; ++f) s += af[f] * W1[f*256 + K];
      tmp[kk*64 + lane] = eluf(s);
    }
    __syncthreads();
    for (int kk = 0; kk < 64; ++kk){
      float w2v = w2s[kk*64 + lane];
      const float4* tr = (const float4*)(&tmp[kk*64 + w*16]);
      float4 t0 = tr[0], t1 = tr[1], t2 = tr[2], t3 = tr[3];
      acc[0]  += t0.x*w2v; acc[1]  += t0.y*w2v; acc[2]  += t0.z*w2v; acc[3]  += t0.w*w2v;
      acc[4]  += t1.x*w2v; acc[5]  += t1.y*w2v; acc[6]  += t1.z*w2v; acc[7]  += t1.w*w2v;
      acc[8]  += t2.x*w2v; acc[9]  += t2.y*w2v; acc[10] += t2.z*w2v; acc[11] += t2.w*w2v;
      acc[12] += t3.x*w2v; acc[13] += t3.y*w2v; acc[14] += t3.z*w2v; acc[15] += t3.w*w2v;
    }
    __syncthreads();
  }
  float asv = as2v[lane], adv = ad2v[lane];
  for (int j = 0; j < 16; ++j){
    int n = base + w*16 + j;
    if (n < N) h2[n*64 + lane] = acc[j];
    float ps = acc[j] * asv, pd = acc[j] * adv;
    for (int o = 32; o > 0; o >>= 1){
      ps += __shfl_down(ps, o, 64);
      pd += __shfl_down(pd, o, 64);
    }
    if (lane == 0 && n < N) a2[n] = make_float2(ps, pd);
  }
}

// K5: layer-2 aggregation only for drone dsts (first ND) + elu + MLP head.
__global__ __launch_bounds__(256) void k5_out(
    const float* __restrict__ h2, const float2* __restrict__ a2,
    const int* __restrict__ cnt, const int* __restrict__ bucket,
    const float* __restrict__ b2, const float* __restrict__ fc1w,
    const float* __restrict__ fc1b, const float* __restrict__ fc2w,
    const float* __restrict__ fc2b, float* __restrict__ out, int ND){
  __shared__ float hb[4][64];
  int lane = threadIdx.x & 63;
  int w = threadIdx.x >> 6;
  int n = blockIdx.x * 4 + w;
  if (n >= ND) return;
  float2 self = a2[n];
  float adv = self.y;
  float e0 = __expf(leaky(self.x + adv));
  float den = e0;
  float acc = e0 * h2[n*64 + lane];
  int deg = min(cnt[n], CAP);
  for (int i = 0; i < deg; ++i){
    int s = bucket[n*CAP + i];
    float e = __expf(leaky(a2[s].x + adv));
    den += e;
    acc += e * h2[s*64 + lane];
  }
  float hv = eluf(acc / den + b2[lane]);
  hb[w][lane] = hv;               // wave-local LDS (lockstep wave64)
  float t1 = fc1b[lane];
  for (int k = 0; k < 64; ++k) t1 += hb[w][k] * fc1w[k*64 + lane];
  t1 = fmaxf(t1, 0.f);
  float p0 = t1 * fc2w[lane*2 + 0];
  float p1 = t1 * fc2w[lane*2 + 1];
  for (int o = 32; o > 0; o >>= 1){
    p0 += __shfl_down(p0, o, 64);
    p1 += __shfl_down(p1, o, 64);
  }
  if (lane == 0){
    out[n*2 + 0] = tanhf(p0 + fc2b[0]) * 2.f;
    out[n*2 + 1] = tanhf(p1 + fc2b[1]) * 2.f;
  }
}

extern "C" void kernel_launch(void* const* d_in, const int* in_sizes, int n_in,
                              void* d_out, int out_size, void* d_ws, size_t ws_size,
                              hipStream_t stream){
  const float* x    = (const float*)d_in[0];
  const int*   ei   = (const int*)d_in[1];    // harness passes integers as int32
  const float* W1   = (const float*)d_in[3];
  const float* as1  = (const float*)d_in[4];
  const float* ad1  = (const float*)d_in[5];
  const float* b1   = (const float*)d_in[6];
  const float* W2   = (const float*)d_in[7];
  const float* as2  = (const float*)d_in[8];
  const float* ad2  = (const float*)d_in[9];
  const float* b2   = (const float*)d_in[10];
  const float* fc1w = (const float*)d_in[11];
  const float* fc1b = (const float*)d_in[12];
  const float* fc2w = (const float*)d_in[13];
  const float* fc2b = (const float*)d_in[14];
  float* out = (float*)d_out;

  int N  = in_sizes[0] / 6;
  int E  = in_sizes[1] / 2;
  int ND = out_size / 2;

  char* p = (char*)d_ws;
  auto alloc = [&](size_t bytes){ void* r = (void*)p; p += (bytes + 255) & ~(size_t)255; return r; };
  int*    cnt    = (int*)   alloc((size_t)N * 4);
  int*    bucket = (int*)   alloc((size_t)N * CAP * 4);
  float4* rec    = (float4*)alloc((size_t)N * 64);
  float*  aggr   = (float*) alloc((size_t)N * 128);
  float*  h2     = (float*) alloc((size_t)N * 256);
  float2* a2     = (float2*)alloc((size_t)N * 8);

  size_t needed = (size_t)(p - (char*)d_ws);
  if (needed > ws_size) return;   // clean fail instead of GPU fault

  hipMemsetAsync(cnt, 0, (size_t)N * 4, stream);
  k1_att1<<<(N + 255)/256, 256, 0, stream>>>(x, W1, as1, ad1, rec, N);
  k2_bucket<<<8 * 784, 256, 0, stream>>>(ei, E, N, cnt, bucket);
  k3_agg1<<<(N + 255)/256, 256, 0, stream>>>(rec, cnt, bucket, aggr, N);
  k4_layer2pre<<<(N + 63)/64, 256, 0, stream>>>(aggr, W1, b1, W2, as2, ad2, h2, a2, N);
  k5_out<<<(ND + 3)/4, 256, 0, stream>>>(h2, a2, cnt, bucket, b2,
                                         fc1w, fc1b, fc2w, fc2b, out, ND);
}

// Round 4
// 272.187 us; speedup vs baseline: 1.5235x; 1.2921x over previous
//
#include <hip/hip_runtime.h>
#include <math.h>

#define CAP 48     // max bucketed in-degree; Poisson(16), P(deg>=48) ~ 8e-11/node
#define NPART 8    // dst partitions ~ XCDs

typedef float f32x4 __attribute__((ext_vector_type(4)));
typedef __bf16 bf16x8 __attribute__((ext_vector_type(8)));
typedef unsigned short ushort8 __attribute__((ext_vector_type(8)));

__device__ __forceinline__ float leaky(float x){ return x > 0.f ? x : 0.2f * x; }
__device__ __forceinline__ float eluf(float x){ return x > 0.f ? x : __expf(x) - 1.f; }
__device__ __forceinline__ unsigned short f2bf(float f){  // RNE float->bf16
  unsigned u = __float_as_uint(f);
  u += 0x7FFF + ((u >> 16) & 1);
  return (unsigned short)(u >> 16);
}

// K0b: pre-pack W2 into bf16 MFMA B-fragment lane order.
// Read in k4: frag[((ks*4+ct)*64 + L)*8 + j] = W2[k= ks*32+(L>>4)*8+j][c= ct*16+(L&15)]
__global__ __launch_bounds__(256) void k0b_bfrag(const float* __restrict__ W2,
    unsigned short* __restrict__ Bfrag){
  int t = blockIdx.x * 256 + threadIdx.x;
  if (t >= 16384) return;
  int j  = t & 7;
  int L  = (t >> 3) & 63;
  int ct = (t >> 9) & 3;
  int ks = t >> 11;
  int k = ks*32 + ((L >> 4) & 3)*8 + j;
  int c = ct*16 + (L & 15);
  Bfrag[t] = f2bf(W2[k*64 + c]);
}

// K1: compute vw in LDS, emit packed 64B node record:
// rec[n] = {x0..x5, as0..as3, ad0..ad3, pad, pad}  (4 x float4)
__global__ __launch_bounds__(256) void k1_att1(const float* __restrict__ x,
    const float* __restrict__ W1, const float* __restrict__ as1,
    const float* __restrict__ ad1, float4* __restrict__ rec, int N){
  __shared__ float vw[48];
  int t = threadIdx.x;
  if (t < 48){
    int side = t / 24, r = t % 24, f = r / 4, h = r % 4;
    const float* att = side ? ad1 : as1;
    float s = 0.f;
    for (int c = 0; c < 64; ++c) s += W1[f*256 + h*64 + c] * att[h*64 + c];
    vw[side*24 + f*4 + h] = s;
  }
  __syncthreads();
  int n = blockIdx.x * 256 + t;
  if (n >= N) return;
  float xf[6];
  for (int f = 0; f < 6; ++f) xf[f] = x[n*6 + f];
  float as[4], ad[4];
  for (int h = 0; h < 4; ++h){
    float s = 0.f, d = 0.f;
    for (int f = 0; f < 6; ++f){ s += xf[f] * vw[f*4 + h]; d += xf[f] * vw[24 + f*4 + h]; }
    as[h] = s; ad[h] = d;
  }
  rec[n*4 + 0] = make_float4(xf[0], xf[1], xf[2], xf[3]);
  rec[n*4 + 1] = make_float4(xf[4], xf[5], as[0], as[1]);
  rec[n*4 + 2] = make_float4(as[2], as[3], ad[0], ad[1]);
  rec[n*4 + 3] = make_float4(ad[2], ad[3], 0.f, 0.f);
}

// K2: XCD-partitioned bucket build (blockIdx&7 -> dst partition; 2.4MB slab/L2).
__global__ __launch_bounds__(256) void k2_bucket(const int* __restrict__ ei,
    int E, int N, int* __restrict__ cnt, int* __restrict__ bucket){
  int part = (N + NPART - 1) / NPART;
  int p = blockIdx.x & (NPART - 1);
  int lo = p * part;
  int hi = min(N, lo + part);
  int g = blockIdx.x >> 3;
  int tid = g * 256 + threadIdx.x;
  int stride = (gridDim.x >> 3) * 256;
  for (int e = tid; e < E; e += stride){
    int dst = ei[E + e];
    if (dst >= lo && dst < hi){
      int pos = atomicAdd(&cnt[dst], 1);
      if (pos < CAP) bucket[dst*CAP + pos] = ei[e];
    }
  }
}

// K3: per-NODE layer-1 softmax-aggregate in input space, all 4 heads at once.
// Output packed 128B/node: aggr[n*32 + h*6 + f] = acc, aggr[n*32 + 24 + h] = den.
__global__ __launch_bounds__(256) void k3_agg1(const float4* __restrict__ rec,
    const int* __restrict__ cnt, const int* __restrict__ bucket,
    float* __restrict__ aggr, int N){
  int n = blockIdx.x * 256 + threadIdx.x;
  if (n >= N) return;
  float4 q0 = rec[n*4+0], q1 = rec[n*4+1], q2 = rec[n*4+2], q3 = rec[n*4+3];
  float xf[6] = {q0.x, q0.y, q0.z, q0.w, q1.x, q1.y};
  float as[4] = {q1.z, q1.w, q2.x, q2.y};
  float ad[4] = {q2.z, q2.w, q3.x, q3.y};
  float acc[4][6], den[4];
  for (int h = 0; h < 4; ++h){
    float e0 = __expf(leaky(as[h] + ad[h]));   // self-loop
    den[h] = e0;
    for (int f = 0; f < 6; ++f) acc[h][f] = e0 * xf[f];
  }
  int deg = min(cnt[n], CAP);
  const int* bk = bucket + n*CAP;
  int i = 0;
  for (; i + 2 <= deg; i += 2){
    int s0 = bk[i], s1 = bk[i+1];
    float4 a0 = rec[s0*4+0], a1 = rec[s0*4+1], a2 = rec[s0*4+2];
    float4 b0 = rec[s1*4+0], b1 = rec[s1*4+1], b2 = rec[s1*4+2];
    float sx0[6] = {a0.x, a0.y, a0.z, a0.w, a1.x, a1.y};
    float sa0[4] = {a1.z, a1.w, a2.x, a2.y};
    float sx1[6] = {b0.x, b0.y, b0.z, b0.w, b1.x, b1.y};
    float sa1[4] = {b1.z, b1.w, b2.x, b2.y};
    for (int h = 0; h < 4; ++h){
      float e0 = __expf(leaky(sa0[h] + ad[h]));
      float e1 = __expf(leaky(sa1[h] + ad[h]));
      den[h] += e0 + e1;
      for (int f = 0; f < 6; ++f) acc[h][f] += e0 * sx0[f] + e1 * sx1[f];
    }
  }
  if (i < deg){
    int s = bk[i];
    float4 a0 = rec[s*4+0], a1 = rec[s*4+1], a2 = rec[s*4+2];
    float sx[6] = {a0.x, a0.y, a0.z, a0.w, a1.x, a1.y};
    float sa[4] = {a1.z, a1.w, a2.x, a2.y};
    for (int h = 0; h < 4; ++h){
      float e = __expf(leaky(sa[h] + ad[h]));
      den[h] += e;
      for (int f = 0; f < 6; ++f) acc[h][f] += e * sx[f];
    }
  }
  float4* o = (float4*)(aggr + (size_t)n*32);
  o[0] = make_float4(acc[0][0], acc[0][1], acc[0][2], acc[0][3]);
  o[1] = make_float4(acc[0][4], acc[0][5], acc[1][0], acc[1][1]);
  o[2] = make_float4(acc[1][2], acc[1][3], acc[1][4], acc[1][5]);
  o[3] = make_float4(acc[2][0], acc[2][1], acc[2][2], acc[2][3]);
  o[4] = make_float4(acc[2][4], acc[2][5], acc[3][0], acc[3][1]);
  o[5] = make_float4(acc[3][2], acc[3][3], acc[3][4], acc[3][5]);
  o[6] = make_float4(den[0], den[1], den[2], den[3]);
}

// K4 (MFMA rewrite): per-wave 16 nodes. A-frag (helu1, bf16) computed in
// registers from aggr+W1+b1; B-frags (W2) pre-packed in lane order; no LDS,
// no barriers. C/D: col=lane&15 (channel), row=(lane>>4)*4+reg (node). [m89]
__global__ __launch_bounds__(256) void k4_mfma(
    const float* __restrict__ aggr, const float* __restrict__ W1,
    const float* __restrict__ b1, const unsigned short* __restrict__ Bfrag,
    const float* __restrict__ as2v, const float* __restrict__ ad2v,
    float* __restrict__ h2, float2* __restrict__ a2, int N){
  int t = threadIdx.x;
  int L = t & 63;
  int w = t >> 6;
  int base = blockIdx.x * 64;
  int m = L & 15;        // A-frag row (node within wave tile); also C/D col
  int quad = L >> 4;
  int na = base + w*16 + m;            // node whose helu1 this lane supplies
  int nc = min(na, N-1);
  const float4* A4 = (const float4*)(aggr + (size_t)nc*32);
  float4 q0=A4[0], q1=A4[1], q2=A4[2], q3=A4[3], q4=A4[4], q5=A4[5], q6=A4[6];
  float d0=1.f/q6.x, d1=1.f/q6.y, d2=1.f/q6.z, d3=1.f/q6.w;
  float af[24];
  af[0]=q0.x*d0;  af[1]=q0.y*d0;  af[2]=q0.z*d0;  af[3]=q0.w*d0;  af[4]=q1.x*d0;  af[5]=q1.y*d0;
  af[6]=q1.z*d1;  af[7]=q1.w*d1;  af[8]=q2.x*d1;  af[9]=q2.y*d1;  af[10]=q2.z*d1; af[11]=q2.w*d1;
  af[12]=q3.x*d2; af[13]=q3.y*d2; af[14]=q3.z*d2; af[15]=q3.w*d2; af[16]=q4.x*d2; af[17]=q4.y*d2;
  af[18]=q4.z*d3; af[19]=q4.w*d3; af[20]=q5.x*d3; af[21]=q5.y*d3; af[22]=q5.z*d3; af[23]=q5.w*d3;

  f32x4 acc[4];
  #pragma unroll
  for (int ct = 0; ct < 4; ++ct) acc[ct] = (f32x4){0.f, 0.f, 0.f, 0.f};

  #pragma unroll
  for (int ks = 0; ks < 8; ++ks){
    int kb = ks*32 + quad*8;           // 8-aligned, stays within one head chunk
    int kc = kb >> 6;
    const float* afk = af + kc*6;
    float4 bb0 = *(const float4*)(b1 + kb);
    float4 bb1 = *(const float4*)(b1 + kb + 4);
    float s0=bb0.x, s1=bb0.y, s2=bb0.z, s3=bb0.w;
    float s4=bb1.x, s5=bb1.y, s6=bb1.z, s7=bb1.w;
    #pragma unroll
    for (int f = 0; f < 6; ++f){
      float a = afk[f];
      float4 w0 = *(const float4*)(W1 + f*256 + kb);
      float4 w1 = *(const float4*)(W1 + f*256 + kb + 4);
      s0 += a*w0.x; s1 += a*w0.y; s2 += a*w0.z; s3 += a*w0.w;
      s4 += a*w1.x; s5 += a*w1.y; s6 += a*w1.z; s7 += a*w1.w;
    }
    ushort8 ap;
    ap[0]=f2bf(eluf(s0)); ap[1]=f2bf(eluf(s1)); ap[2]=f2bf(eluf(s2)); ap[3]=f2bf(eluf(s3));
    ap[4]=f2bf(eluf(s4)); ap[5]=f2bf(eluf(s5)); ap[6]=f2bf(eluf(s6)); ap[7]=f2bf(eluf(s7));
    bf16x8 av = __builtin_bit_cast(bf16x8, ap);
    #pragma unroll
    for (int ct = 0; ct < 4; ++ct){
      bf16x8 bv = *(const bf16x8*)(Bfrag + (size_t)(((ks*4 + ct)*64 + L) * 8));
      acc[ct] = __builtin_amdgcn_mfma_f32_16x16x32_bf16(av, bv, acc[ct], 0, 0, 0);
    }
  }

  // epilogue: h2 writes + attention dots (reduce over the 16 channel lanes)
  float asv[4], adv[4];
  #pragma unroll
  for (int ct = 0; ct < 4; ++ct){ asv[ct] = as2v[ct*16 + m]; adv[ct] = ad2v[ct*16 + m]; }
  float ps[4] = {0,0,0,0}, pd[4] = {0,0,0,0};
  #pragma unroll
  for (int ct = 0; ct < 4; ++ct)
    #pragma unroll
    for (int r = 0; r < 4; ++r){
      ps[r] += acc[ct][r] * asv[ct];
      pd[r] += acc[ct][r] * adv[ct];
    }
  #pragma unroll
  for (int r = 0; r < 4; ++r){
    int nr = base + w*16 + quad*4 + r;
    if (nr < N){
      #pragma unroll
      for (int ct = 0; ct < 4; ++ct)
        h2[(size_t)nr*64 + ct*16 + m] = acc[ct][r];
    }
  }
  #pragma unroll
  for (int mask = 1; mask <= 8; mask <<= 1){
    #pragma unroll
    for (int r = 0; r < 4; ++r){
      ps[r] += __shfl_xor(ps[r], mask, 64);
      pd[r] += __shfl_xor(pd[r], mask, 64);
    }
  }
  if (m == 0){
    #pragma unroll
    for (int r = 0; r < 4; ++r){
      int nr = base + w*16 + quad*4 + r;
      if (nr < N) a2[nr] = make_float2(ps[r], pd[r]);
    }
  }
}

// K5: layer-2 aggregation only for drone dsts (first ND) + elu + MLP head.
__global__ __launch_bounds__(256) void k5_out(
    const float* __restrict__ h2, const float2* __restrict__ a2,
    const int* __restrict__ cnt, const int* __restrict__ bucket,
    const float* __restrict__ b2, const float* __restrict__ fc1w,
    const float* __restrict__ fc1b, const float* __restrict__ fc2w,
    const float* __restrict__ fc2b, float* __restrict__ out, int ND){
  __shared__ float hb[4][64];
  int lane = threadIdx.x & 63;
  int w = threadIdx.x >> 6;
  int n = blockIdx.x * 4 + w;
  if (n >= ND) return;
  float2 self = a2[n];
  float adv = self.y;
  float e0 = __expf(leaky(self.x + adv));
  float den = e0;
  float acc = e0 * h2[n*64 + lane];
  int deg = min(cnt[n], CAP);
  for (int i = 0; i < deg; ++i){
    int s = bucket[n*CAP + i];
    float e = __expf(leaky(a2[s].x + adv));
    den += e;
    acc += e * h2[s*64 + lane];
  }
  float hv = eluf(acc / den + b2[lane]);
  hb[w][lane] = hv;               // wave-local LDS (lockstep wave64)
  float t1 = fc1b[lane];
  for (int k = 0; k < 64; ++k) t1 += hb[w][k] * fc1w[k*64 + lane];
  t1 = fmaxf(t1, 0.f);
  float p0 = t1 * fc2w[lane*2 + 0];
  float p1 = t1 * fc2w[lane*2 + 1];
  for (int o = 32; o > 0; o >>= 1){
    p0 += __shfl_down(p0, o, 64);
    p1 += __shfl_down(p1, o, 64);
  }
  if (lane == 0){
    out[n*2 + 0] = tanhf(p0 + fc2b[0]) * 2.f;
    out[n*2 + 1] = tanhf(p1 + fc2b[1]) * 2.f;
  }
}

extern "C" void kernel_launch(void* const* d_in, const int* in_sizes, int n_in,
                              void* d_out, int out_size, void* d_ws, size_t ws_size,
                              hipStream_t stream){
  const float* x    = (const float*)d_in[0];
  const int*   ei   = (const int*)d_in[1];    // harness passes integers as int32
  const float* W1   = (const float*)d_in[3];
  const float* as1  = (const float*)d_in[4];
  const float* ad1  = (const float*)d_in[5];
  const float* b1   = (const float*)d_in[6];
  const float* W2   = (const float*)d_in[7];
  const float* as2  = (const float*)d_in[8];
  const float* ad2  = (const float*)d_in[9];
  const float* b2   = (const float*)d_in[10];
  const float* fc1w = (const float*)d_in[11];
  const float* fc1b = (const float*)d_in[12];
  const float* fc2w = (const float*)d_in[13];
  const float* fc2b = (const float*)d_in[14];
  float* out = (float*)d_out;

  int N  = in_sizes[0] / 6;
  int E  = in_sizes[1] / 2;
  int ND = out_size / 2;

  char* p = (char*)d_ws;
  auto alloc = [&](size_t bytes){ void* r = (void*)p; p += (bytes + 255) & ~(size_t)255; return r; };
  int*            cnt    = (int*)           alloc((size_t)N * 4);
  int*            bucket = (int*)           alloc((size_t)N * CAP * 4);
  float4*         rec    = (float4*)        alloc((size_t)N * 64);
  float*          aggr   = (float*)         alloc((size_t)N * 128);
  float*          h2     = (float*)         alloc((size_t)N * 256);
  float2*         a2     = (float2*)        alloc((size_t)N * 8);
  unsigned short* Bfrag  = (unsigned short*)alloc(16384 * 2);

  size_t needed = (size_t)(p - (char*)d_ws);
  if (needed > ws_size) return;   // clean fail instead of GPU fault

  hipMemsetAsync(cnt, 0, (size_t)N * 4, stream);
  k0b_bfrag<<<64, 256, 0, stream>>>(W2, Bfrag);
  k1_att1<<<(N + 255)/256, 256, 0, stream>>>(x, W1, as1, ad1, rec, N);
  k2_bucket<<<8 * 784, 256, 0, stream>>>(ei, E, N, cnt, bucket);
  k3_agg1<<<(N + 255)/256, 256, 0, stream>>>(rec, cnt, bucket, aggr, N);
  k4_mfma<<<(N + 63)/64, 256, 0, stream>>>(aggr, W1, b1, Bfrag, as2, ad2, h2, a2, N);
  k5_out<<<(ND + 3)/4, 256, 0, stream>>>(h2, a2, cnt, bucket, b2,
                                         fc1w, fc1b, fc2w, fc2b, out, ND);
}